// Round 1
// baseline (281.272 us; speedup 1.0000x reference)
//
#include <hip/hip_runtime.h>
#include <hip/hip_bf16.h>

#define BATCH 32
#define CCH   1536
#define ACH   128
#define TLEN  1000
#define TPAD  1024
#define EPSV  1e-5f

typedef __attribute__((ext_vector_type(8))) short bf16x8;
typedef __attribute__((ext_vector_type(4))) float f32x4;

__device__ __forceinline__ unsigned short f2bf(float f) {
    union { float f; unsigned u; } v; v.f = f;
    unsigned r = v.u + 0x7fffu + ((v.u >> 16) & 1u);
    return (unsigned short)(r >> 16);
}

// ---------------- Kernel A: per-(b,c) mean/std over T + cast/transpose x -> xt[b][t][c] bf16
__global__ __launch_bounds__(256) void kA(const float* __restrict__ x,
                                          unsigned short* __restrict__ xt,
                                          float* __restrict__ meanw,
                                          float* __restrict__ stdw) {
    int b = blockIdx.y, cb = blockIdx.x * 32;
    int tid = threadIdx.x;
    int row = tid >> 3, l8 = tid & 7;          // 32 rows, 8 threads/row
    __shared__ float tile[64][33];
    const float* xr = x + ((size_t)(b * CCH + cb + row)) * TLEN;
    float s1 = 0.f, s2 = 0.f;
    for (int tt = 0; tt < 16; ++tt) {
        int t0 = tt * 64;
        #pragma unroll
        for (int p = 0; p < 2; ++p) {
            int tf = t0 + (l8 + 8 * p) * 4;    // local t = tf - t0
            float4 vv = make_float4(0.f, 0.f, 0.f, 0.f);
            if (tf < TLEN) vv = *reinterpret_cast<const float4*>(xr + tf);
            s1 += vv.x + vv.y + vv.z + vv.w;
            s2 += vv.x * vv.x + vv.y * vv.y + vv.z * vv.z + vv.w * vv.w;
            int tl = tf - t0;
            tile[tl + 0][row] = vv.x;
            tile[tl + 1][row] = vv.y;
            tile[tl + 2][row] = vv.z;
            tile[tl + 3][row] = vv.w;
        }
        __syncthreads();
        // readback transposed, cast, store 16B coalesced
        int tl = tid >> 2, c8 = (tid & 3) * 8;
        unsigned o[4];
        #pragma unroll
        for (int j = 0; j < 4; ++j) {
            unsigned lo = f2bf(tile[tl][c8 + 2 * j]);
            unsigned hi = f2bf(tile[tl][c8 + 2 * j + 1]);
            o[j] = lo | (hi << 16);
        }
        uint4 u; u.x = o[0]; u.y = o[1]; u.z = o[2]; u.w = o[3];
        *reinterpret_cast<uint4*>(xt + ((size_t)(b * TPAD + t0 + tl)) * CCH + cb + c8) = u;
        __syncthreads();
    }
    #pragma unroll
    for (int d = 1; d < 8; d <<= 1) { s1 += __shfl_xor(s1, d); s2 += __shfl_xor(s2, d); }
    if (l8 == 0) {
        float mean = s1 / (float)TLEN;
        float var = (s2 - s1 * s1 / (float)TLEN) / (float)(TLEN - 1);
        meanw[b * CCH + cb + row] = mean;
        stdw[b * CCH + cb + row] = sqrtf(var + EPSV);
    }
}

// Stats-only fallback (if workspace too small for xt)
__global__ __launch_bounds__(256) void kA2(const float* __restrict__ x,
                                           float* __restrict__ meanw,
                                           float* __restrict__ stdw) {
    int b = blockIdx.y, cb = blockIdx.x * 32;
    int tid = threadIdx.x;
    int row = tid >> 3, l8 = tid & 7;
    const float* xr = x + ((size_t)(b * CCH + cb + row)) * TLEN;
    float s1 = 0.f, s2 = 0.f;
    for (int tf = l8 * 4; tf < TLEN; tf += 32) {
        float4 vv = *reinterpret_cast<const float4*>(xr + tf);
        s1 += vv.x + vv.y + vv.z + vv.w;
        s2 += vv.x * vv.x + vv.y * vv.y + vv.z * vv.z + vv.w * vv.w;
    }
    #pragma unroll
    for (int d = 1; d < 8; d <<= 1) { s1 += __shfl_xor(s1, d); s2 += __shfl_xor(s2, d); }
    if (l8 == 0) {
        float mean = s1 / (float)TLEN;
        float var = (s2 - s1 * s1 / (float)TLEN) / (float)(TLEN - 1);
        meanw[b * CCH + cb + row] = mean;
        stdw[b * CCH + cb + row] = sqrtf(var + EPSV);
    }
}

// ---------------- B1: cast w1 x-part to bf16 [A][C]
__global__ __launch_bounds__(256) void kB1(const float* __restrict__ w1,
                                           unsigned short* __restrict__ w1x) {
    int e = blockIdx.x * 256 + threadIdx.x;   // < ACH*CCH
    int a = e / CCH, c = e - a * CCH;
    w1x[e] = f2bf(w1[(size_t)a * (3 * CCH) + c]);
}

// ---------------- B2: hbias[b][a] = b1[a] + sum_c w1m*mean + w1s*std
__global__ __launch_bounds__(64) void kB2(const float* __restrict__ w1,
                                          const float* __restrict__ b1,
                                          const float* __restrict__ meanw,
                                          const float* __restrict__ stdw,
                                          float* __restrict__ hbias) {
    int a = blockIdx.x, b = blockIdx.y, l = threadIdx.x;
    const float* wr = w1 + (size_t)a * 3 * CCH;
    const float* mb = meanw + b * CCH;
    const float* sb = stdw + b * CCH;
    float acc = 0.f;
    for (int k = l; k < CCH; k += 64)
        acc += wr[CCH + k] * mb[k] + wr[2 * CCH + k] * sb[k];
    #pragma unroll
    for (int d = 1; d < 64; d <<= 1) acc += __shfl_xor(acc, d);
    if (l == 0) hbias[b * ACH + a] = acc + b1[a];
}

// ---------------- B3: fold BN1 into w2 -> w2e bf16 [C][A], b2e[C]
__global__ __launch_bounds__(64) void kB3(const float* __restrict__ w2,
                                          const float* __restrict__ b2,
                                          const float* __restrict__ g1,
                                          const float* __restrict__ be1,
                                          const float* __restrict__ rm1,
                                          const float* __restrict__ rv1,
                                          unsigned short* __restrict__ w2e,
                                          float* __restrict__ b2e) {
    int c = blockIdx.x, l = threadIdx.x;
    float acc = 0.f;
    #pragma unroll
    for (int p = 0; p < 2; ++p) {
        int a = p * 64 + l;
        float s1 = g1[a] / sqrtf(rv1[a] + EPSV);
        float w = w2[(size_t)c * ACH + a];
        w2e[(size_t)c * ACH + a] = f2bf(w * s1);
        acc += w * (be1[a] - s1 * rm1[a]);
    }
    #pragma unroll
    for (int d = 1; d < 64; d <<= 1) acc += __shfl_xor(acc, d);
    if (l == 0) b2e[c] = b2[c] + acc;
}

// ---------------- C: GEMM1  h[b][t][a] = relu( w1x @ x + hbias )  via MFMA bf16
__global__ __launch_bounds__(256) void kC(const unsigned short* __restrict__ xt,
                                          const unsigned short* __restrict__ w1x,
                                          const float* __restrict__ hbias,
                                          unsigned short* __restrict__ h) {
    int b = blockIdx.y;
    int t0 = blockIdx.x * 64;
    int tid = threadIdx.x;
    int wv = tid >> 6, l = tid & 63, g = l >> 4, r = l & 15;
    const unsigned short* aptr = w1x + (size_t)(32 * wv + r) * CCH + 8 * g;
    const unsigned short* bptr = xt + ((size_t)(b * TPAD + t0 + r)) * CCH + 8 * g;
    f32x4 acc[2][4];
    #pragma unroll
    for (int i = 0; i < 2; ++i)
        #pragma unroll
        for (int j = 0; j < 4; ++j) acc[i][j] = f32x4{0.f, 0.f, 0.f, 0.f};
    for (int kk = 0; kk < CCH / 32; ++kk) {
        bf16x8 Af[2], Bf[4];
        #pragma unroll
        for (int at = 0; at < 2; ++at)
            Af[at] = *reinterpret_cast<const bf16x8*>(aptr + (size_t)(16 * at) * CCH + 32 * kk);
        #pragma unroll
        for (int tt = 0; tt < 4; ++tt)
            Bf[tt] = *reinterpret_cast<const bf16x8*>(bptr + (size_t)(16 * tt) * CCH + 32 * kk);
        #pragma unroll
        for (int at = 0; at < 2; ++at)
            #pragma unroll
            for (int tt = 0; tt < 4; ++tt)
                acc[at][tt] = __builtin_amdgcn_mfma_f32_16x16x32_bf16(Af[at], Bf[tt], acc[at][tt], 0, 0, 0);
    }
    #pragma unroll
    for (int at = 0; at < 2; ++at) {
        f32x4 hb = *reinterpret_cast<const f32x4*>(hbias + b * ACH + 32 * wv + 16 * at + 4 * g);
        #pragma unroll
        for (int tt = 0; tt < 4; ++tt) {
            int t = t0 + 16 * tt + r;
            unsigned lo0, lo1;
            float v0 = acc[at][tt][0] + hb[0]; v0 = v0 > 0.f ? v0 : 0.f;
            float v1 = acc[at][tt][1] + hb[1]; v1 = v1 > 0.f ? v1 : 0.f;
            float v2 = acc[at][tt][2] + hb[2]; v2 = v2 > 0.f ? v2 : 0.f;
            float v3 = acc[at][tt][3] + hb[3]; v3 = v3 > 0.f ? v3 : 0.f;
            lo0 = (unsigned)f2bf(v0) | ((unsigned)f2bf(v1) << 16);
            lo1 = (unsigned)f2bf(v2) | ((unsigned)f2bf(v3) << 16);
            uint2 u; u.x = lo0; u.y = lo1;
            *reinterpret_cast<uint2*>(h + ((size_t)(b * TPAD + t)) * ACH + 32 * wv + 16 * at + 4 * g) = u;
        }
    }
}

// Fallback GEMM1: gather x fp32 directly (slow but correct), used if no room for xt
__global__ __launch_bounds__(256) void kC2(const float* __restrict__ x,
                                           const unsigned short* __restrict__ w1x,
                                           const float* __restrict__ hbias,
                                           unsigned short* __restrict__ h) {
    int b = blockIdx.y;
    int t0 = blockIdx.x * 64;
    int tid = threadIdx.x;
    int wv = tid >> 6, l = tid & 63, g = l >> 4, r = l & 15;
    const unsigned short* aptr = w1x + (size_t)(32 * wv + r) * CCH + 8 * g;
    f32x4 acc[2][4];
    #pragma unroll
    for (int i = 0; i < 2; ++i)
        #pragma unroll
        for (int j = 0; j < 4; ++j) acc[i][j] = f32x4{0.f, 0.f, 0.f, 0.f};
    for (int kk = 0; kk < CCH / 32; ++kk) {
        bf16x8 Af[2], Bf[4];
        #pragma unroll
        for (int at = 0; at < 2; ++at)
            Af[at] = *reinterpret_cast<const bf16x8*>(aptr + (size_t)(16 * at) * CCH + 32 * kk);
        #pragma unroll
        for (int tt = 0; tt < 4; ++tt) {
            int t = t0 + 16 * tt + r;
            unsigned short tmp[8];
            #pragma unroll
            for (int j = 0; j < 8; ++j) {
                float xv = 0.f;
                if (t < TLEN) xv = x[((size_t)(b * CCH + 32 * kk + 8 * g + j)) * TLEN + t];
                tmp[j] = f2bf(xv);
            }
            Bf[tt] = *reinterpret_cast<const bf16x8*>(tmp);
        }
        #pragma unroll
        for (int at = 0; at < 2; ++at)
            #pragma unroll
            for (int tt = 0; tt < 4; ++tt)
                acc[at][tt] = __builtin_amdgcn_mfma_f32_16x16x32_bf16(Af[at], Bf[tt], acc[at][tt], 0, 0, 0);
    }
    #pragma unroll
    for (int at = 0; at < 2; ++at) {
        f32x4 hb = *reinterpret_cast<const f32x4*>(hbias + b * ACH + 32 * wv + 16 * at + 4 * g);
        #pragma unroll
        for (int tt = 0; tt < 4; ++tt) {
            int t = t0 + 16 * tt + r;
            float v0 = acc[at][tt][0] + hb[0]; v0 = v0 > 0.f ? v0 : 0.f;
            float v1 = acc[at][tt][1] + hb[1]; v1 = v1 > 0.f ? v1 : 0.f;
            float v2 = acc[at][tt][2] + hb[2]; v2 = v2 > 0.f ? v2 : 0.f;
            float v3 = acc[at][tt][3] + hb[3]; v3 = v3 > 0.f ? v3 : 0.f;
            uint2 u;
            u.x = (unsigned)f2bf(v0) | ((unsigned)f2bf(v1) << 16);
            u.y = (unsigned)f2bf(v2) | ((unsigned)f2bf(v3) << 16);
            *reinterpret_cast<uint2*>(h + ((size_t)(b * TPAD + t)) * ACH + 32 * wv + 16 * at + 4 * g) = u;
        }
    }
}

// ---------------- D: GEMM2 + online softmax + weighted stat pooling + BN2
__global__ __launch_bounds__(256) void kD(const float* __restrict__ x,
                                          const unsigned short* __restrict__ h,
                                          const unsigned short* __restrict__ w2e,
                                          const float* __restrict__ b2e,
                                          const float* __restrict__ rm2,
                                          const float* __restrict__ rv2,
                                          const float* __restrict__ g2,
                                          const float* __restrict__ be2,
                                          float* __restrict__ out) {
    int b = blockIdx.y;
    int tid = threadIdx.x;
    int wv = tid >> 6, l = tid & 63, g = l >> 4, r = l & 15;
    int c0 = blockIdx.x * 64 + 16 * wv;
    bf16x8 W[4];
    #pragma unroll
    for (int kk = 0; kk < 4; ++kk)
        W[kk] = *reinterpret_cast<const bf16x8*>(w2e + (size_t)(c0 + r) * ACH + 32 * kk + 8 * g);
    f32x4 b2v = *reinterpret_cast<const f32x4*>(b2e + c0 + 4 * g);
    const float* xb = x + (size_t)(b * CCH + c0 + 4 * g) * TLEN;
    const unsigned short* hb = h + (size_t)(b * TPAD) * ACH + 8 * g;
    float m[4], s[4], wx[4], wxx[4];
    #pragma unroll
    for (int i = 0; i < 4; ++i) { m[i] = -3.0e38f; s[i] = 0.f; wx[i] = 0.f; wxx[i] = 0.f; }
    for (int tc = 0; tc < TPAD / 32; ++tc) {
        f32x4 a2[2];
        a2[0] = f32x4{0.f, 0.f, 0.f, 0.f};
        a2[1] = f32x4{0.f, 0.f, 0.f, 0.f};
        #pragma unroll
        for (int tt = 0; tt < 2; ++tt) {
            int t = tc * 32 + tt * 16 + r;
            #pragma unroll
            for (int kk = 0; kk < 4; ++kk) {
                bf16x8 Bf = *reinterpret_cast<const bf16x8*>(hb + (size_t)t * ACH + 32 * kk);
                a2[tt] = __builtin_amdgcn_mfma_f32_16x16x32_bf16(W[kk], Bf, a2[tt], 0, 0, 0);
            }
        }
        int tb = tc * 32 + r;
        bool val0 = (tb < TLEN), val1 = (tb + 16 < TLEN);
        #pragma unroll
        for (int i = 0; i < 4; ++i) {
            float v0 = val0 ? (a2[0][i] + b2v[i]) : -3.0e38f;
            float v1 = val1 ? (a2[1][i] + b2v[i]) : -3.0e38f;
            float cm = fmaxf(v0, v1);
            cm = fmaxf(cm, __shfl_xor(cm, 1));
            cm = fmaxf(cm, __shfl_xor(cm, 2));
            cm = fmaxf(cm, __shfl_xor(cm, 4));
            cm = fmaxf(cm, __shfl_xor(cm, 8));
            float mn = fmaxf(m[i], cm);
            float sc = __expf(m[i] - mn);
            float e0 = __expf(v0 - mn);
            float e1 = __expf(v1 - mn);
            float x0 = val0 ? xb[(size_t)i * TLEN + tb] : 0.f;
            float x1 = val1 ? xb[(size_t)i * TLEN + tb + 16] : 0.f;
            float xe0 = x0 * e0, xe1 = x1 * e1;
            s[i]   = s[i]   * sc + e0 + e1;
            wx[i]  = wx[i]  * sc + xe0 + xe1;
            wxx[i] = wxx[i] * sc + x0 * xe0 + x1 * xe1;
            m[i] = mn;
        }
    }
    #pragma unroll
    for (int i = 0; i < 4; ++i) {
        float ss = s[i], sx = wx[i], sxx = wxx[i];
        #pragma unroll
        for (int d = 1; d < 16; d <<= 1) {
            ss += __shfl_xor(ss, d);
            sx += __shfl_xor(sx, d);
            sxx += __shfl_xor(sxx, d);
        }
        if (r == 0) {
            int c = c0 + 4 * g + i;
            float mu = sx / ss;
            float ssq = sxx / ss;
            float sig = sqrtf(fabsf(ssq - mu * mu) + EPSV);
            float o1 = (mu - rm2[c]) * g2[c] / sqrtf(rv2[c] + EPSV) + be2[c];
            int c2 = CCH + c;
            float o2 = (sig - rm2[c2]) * g2[c2] / sqrtf(rv2[c2] + EPSV) + be2[c2];
            out[b * 2 * CCH + c] = o1;
            out[b * 2 * CCH + c2] = o2;
        }
    }
}

extern "C" void kernel_launch(void* const* d_in, const int* in_sizes, int n_in,
                              void* d_out, int out_size, void* d_ws, size_t ws_size,
                              hipStream_t stream) {
    const float* x   = (const float*)d_in[0];
    const float* w1  = (const float*)d_in[1];
    const float* b1  = (const float*)d_in[2];
    const float* g1  = (const float*)d_in[3];
    const float* be1 = (const float*)d_in[4];
    const float* rm1 = (const float*)d_in[5];
    const float* rv1 = (const float*)d_in[6];
    const float* w2  = (const float*)d_in[7];
    const float* b2  = (const float*)d_in[8];
    const float* g2  = (const float*)d_in[9];
    const float* be2 = (const float*)d_in[10];
    const float* rm2 = (const float*)d_in[11];
    const float* rv2 = (const float*)d_in[12];
    float* out = (float*)d_out;

    const size_t sz_xt    = (size_t)BATCH * TPAD * CCH * 2;   // 100.7 MB
    const size_t sz_h     = (size_t)BATCH * TPAD * ACH * 2;   // 8.4 MB
    const size_t sz_w1x   = (size_t)ACH * CCH * 2;
    const size_t sz_w2e   = (size_t)CCH * ACH * 2;
    const size_t sz_mean  = (size_t)BATCH * CCH * 4;
    const size_t sz_std   = sz_mean;
    const size_t sz_hbias = (size_t)BATCH * ACH * 4;
    const size_t sz_b2e   = (size_t)CCH * 4;
    const size_t need_small = sz_h + sz_w1x + sz_w2e + sz_mean + sz_std + sz_hbias + sz_b2e;
    bool use_xt = (ws_size >= need_small + sz_xt);

    char* ws = (char*)d_ws;
    unsigned short* xt = nullptr;
    if (use_xt) { xt = (unsigned short*)ws; ws += sz_xt; }
    unsigned short* hbuf = (unsigned short*)ws; ws += sz_h;
    unsigned short* w1x  = (unsigned short*)ws; ws += sz_w1x;
    unsigned short* w2e  = (unsigned short*)ws; ws += sz_w2e;
    float* meanw = (float*)ws; ws += sz_mean;
    float* stdw  = (float*)ws; ws += sz_std;
    float* hbias = (float*)ws; ws += sz_hbias;
    float* b2e   = (float*)ws; ws += sz_b2e;

    if (use_xt)
        kA<<<dim3(48, 32), 256, 0, stream>>>(x, xt, meanw, stdw);
    else
        kA2<<<dim3(48, 32), 256, 0, stream>>>(x, meanw, stdw);
    kB1<<<(ACH * CCH) / 256, 256, 0, stream>>>(w1, w1x);
    kB3<<<CCH, 64, 0, stream>>>(w2, b2, g1, be1, rm1, rv1, w2e, b2e);
    kB2<<<dim3(ACH, BATCH), 64, 0, stream>>>(w1, b1, meanw, stdw, hbias);
    if (use_xt)
        kC<<<dim3(TPAD / 64, BATCH), 256, 0, stream>>>(xt, w1x, hbias, hbuf);
    else
        kC2<<<dim3(TPAD / 64, BATCH), 256, 0, stream>>>(x, w1x, hbias, hbuf);
    kD<<<dim3(CCH / 64, BATCH), 256, 0, stream>>>(x, hbuf, w2e, b2e, rm2, rv2, g2, be2, out);
}